// Round 1
// baseline (4082.294 us; speedup 1.0000x reference)
//
#include <hip/hip_runtime.h>
#include <hip/hip_bf16.h>

#define D_IN 128
#define D_EMB 64

// ---- weight prep: W[64][K] row-major -> Wt4[k4][j] = float4(W[j][4k4..4k4+3]) ----
__global__ __launch_bounds__(256) void wprep_k(const float4* __restrict__ W4,
                                               float4* __restrict__ out, int K4) {
  int idx = blockIdx.x * 256 + threadIdx.x;
  if (idx >= K4 * 64) return;
  int j = idx & 63, k4 = idx >> 6;
  out[idx] = W4[j * K4 + k4];
}

__global__ __launch_bounds__(256) void degree_k(const int* __restrict__ dst,
                                                float* __restrict__ deg, int E) {
  int e = blockIdx.x * 256 + threadIdx.x;
  if (e < E) atomicAdd(deg + dst[e], 1.0f);
}

__global__ __launch_bounds__(256) void invdeg_k(const float* __restrict__ deg,
                                                float* __restrict__ invdeg, int N) {
  int i = blockIdx.x * 256 + threadIdx.x;
  if (i < N) invdeg[i] = 1.0f / fmaxf(deg[i], 1.0f);
}

// ---- dual GEMM: out1 = x @ W1.T ; out2 = bias2 + x @ W2.T  (x: [N,K], W*: [64,K]) ----
// thread: j = t&63 (output col), wave owns 8 nodes. W loads coalesced via Wt4 layout,
// x loads are wave-broadcast (all 64 lanes same address).
template <int K>
__global__ __launch_bounds__(256) void gemm_dual_k(const float4* __restrict__ x4,
                                                   const float4* __restrict__ wt1,
                                                   const float4* __restrict__ wt2,
                                                   const float* __restrict__ bias2,
                                                   float* __restrict__ out1,
                                                   float* __restrict__ out2) {
  constexpr int K4 = K / 4;
  const int t = threadIdx.x;
  const int j = t & 63;
  const int wv = t >> 6;
  const int nb = blockIdx.x * 32 + wv * 8;   // 32 nodes per block, 8 per wave
  float acc1[8], acc2[8];
  const float bj = bias2[j];
#pragma unroll
  for (int i = 0; i < 8; i++) { acc1[i] = 0.0f; acc2[i] = bj; }
  for (int k4 = 0; k4 < K4; k4++) {
    float4 w1 = wt1[k4 * 64 + j];
    float4 w2 = wt2[k4 * 64 + j];
#pragma unroll
    for (int i = 0; i < 8; i++) {
      float4 xv = x4[(size_t)(nb + i) * K4 + k4];
      acc1[i] += xv.x * w1.x + xv.y * w1.y + xv.z * w1.z + xv.w * w1.w;
      acc2[i] += xv.x * w2.x + xv.y * w2.y + xv.z * w2.z + xv.w * w2.w;
    }
  }
#pragma unroll
  for (int i = 0; i < 8; i++) {
    out1[(size_t)(nb + i) * 64 + j] = acc1[i];
    out2[(size_t)(nb + i) * 64 + j] = acc2[i];
  }
}

// ---- edge scatter: agg[dst] += y[src], 64 floats/edge, 16 lanes/edge (float4 each) ----
__global__ __launch_bounds__(256) void scatter_k(const float4* __restrict__ y4,
                                                 const int* __restrict__ src,
                                                 const int* __restrict__ dst,
                                                 float* __restrict__ agg, int E) {
  int tid = blockIdx.x * 256 + threadIdx.x;
  int e = tid >> 4;
  if (e >= E) return;
  int c = tid & 15;
  float4 v = y4[(size_t)src[e] * 16 + c];
  float* p = agg + (size_t)dst[e] * 64 + c * 4;
  atomicAdd(p + 0, v.x);
  atomicAdd(p + 1, v.y);
  atomicAdd(p + 2, v.z);
  atomicAdd(p + 3, v.w);
}

// ---- fused: agg = agg*invdeg[node] + other   (in-place; other already holds bias + x@Wr.T) ----
__global__ __launch_bounds__(256) void h_fuse_k(float4* __restrict__ agg4,
                                                const float4* __restrict__ other4,
                                                const float* __restrict__ invdeg,
                                                int total4) {
  int tid = blockIdx.x * 256 + threadIdx.x;
  if (tid >= total4) return;
  float s = invdeg[tid >> 4];   // 16 float4 per 64-float node row
  float4 a = agg4[tid], o = other4[tid];
  agg4[tid] = make_float4(a.x * s + o.x, a.y * s + o.y, a.z * s + o.z, a.w * s + o.w);
}

// ---- per-graph mean of h2 = agg2*invdeg + h1r, 64 graphs x 2048 nodes x 64 dims ----
__global__ __launch_bounds__(256) void graph_mean_k(const float* __restrict__ agg2,
                                                    const float* __restrict__ h1r,
                                                    const float* __restrict__ invdeg,
                                                    float* __restrict__ g) {
  int b = blockIdx.x >> 3, part = blockIdx.x & 7;
  int t = threadIdx.x, j = t & 63, sub = t >> 6;
  int nbase = b * 2048 + part * 256 + sub * 64;
  float acc = 0.0f;
  for (int m = 0; m < 64; m++) {
    int node = nbase + m;
    acc += agg2[(size_t)node * 64 + j] * invdeg[node] + h1r[(size_t)node * 64 + j];
  }
  __shared__ float red[256];
  red[t] = acc;
  __syncthreads();
  if (sub == 0) {
    float tot = red[j] + red[j + 64] + red[j + 128] + red[j + 192];
    atomicAdd(g + b * 64 + j, tot * (1.0f / 2048.0f));
  }
}

// ---- h = relu(g @ fc1_W.T + fc1_b)   g:[64,64] fc1_W:[128,64] -> h:[64,128] ----
__global__ __launch_bounds__(256) void mlp1_k(const float* __restrict__ g,
                                              const float* __restrict__ fc1_W,
                                              const float* __restrict__ fc1_b,
                                              float* __restrict__ h) {
  int idx = blockIdx.x * 256 + threadIdx.x;
  int b = idx >> 7, k = idx & 127;
  const float4* g4 = (const float4*)(g + b * 64);
  const float4* w4 = (const float4*)(fc1_W + k * 64);
  float acc = fc1_b[k];
#pragma unroll
  for (int j4 = 0; j4 < 16; j4++) {
    float4 gv = g4[j4], wv = w4[j4];
    acc += gv.x * wv.x + gv.y * wv.y + gv.z * wv.z + gv.w * wv.w;
  }
  h[idx] = fmaxf(acc, 0.0f);
}

// ---- q = h @ fc2_W.T + fc2_b   h:[64,128] fc2_W:[2048,128] -> q:[64,2048] ----
__global__ __launch_bounds__(256) void mlp2_k(const float* __restrict__ h,
                                              const float* __restrict__ fc2_W,
                                              const float* __restrict__ fc2_b,
                                              float* __restrict__ out) {
  __shared__ float4 sh[32];
  int b = blockIdx.x >> 3;
  int a = (blockIdx.x & 7) * 256 + threadIdx.x;
  if (threadIdx.x < 32) sh[threadIdx.x] = ((const float4*)(h + b * 128))[threadIdx.x];
  __syncthreads();
  const float4* w4 = (const float4*)(fc2_W + (size_t)a * 128);
  float acc = fc2_b[a];
#pragma unroll
  for (int k4 = 0; k4 < 32; k4++) {
    float4 hv = sh[k4], wv = w4[k4];
    acc += hv.x * wv.x + hv.y * wv.y + hv.z * wv.z + hv.w * wv.w;
  }
  out[b * 2048 + a] = acc;
}

extern "C" void kernel_launch(void* const* d_in, const int* in_sizes, int n_in,
                              void* d_out, int out_size, void* d_ws, size_t ws_size,
                              hipStream_t stream) {
  const float* x     = (const float*)d_in[0];
  const int*   ei    = (const int*)d_in[1];
  const float* W1l   = (const float*)d_in[2];
  const float* b1l   = (const float*)d_in[3];
  const float* W1r   = (const float*)d_in[4];
  const float* W2l   = (const float*)d_in[5];
  const float* b2l   = (const float*)d_in[6];
  const float* W2r   = (const float*)d_in[7];
  const float* fc1_W = (const float*)d_in[8];
  const float* fc1_b = (const float*)d_in[9];
  const float* fc2_W = (const float*)d_in[10];
  const float* fc2_b = (const float*)d_in[11];
  float* out = (float*)d_out;

  const int N = in_sizes[0] / D_IN;   // 131072
  const int E = in_sizes[1] / 2;      // 2097152
  const int* src = ei;
  const int* dst = ei + E;

  float* ws = (float*)d_ws;
  float* deg    = ws;                         // N
  float* invdeg = ws + (size_t)N;             // N
  float* bufA   = ws + (size_t)2 * N;         // 64N : y1, then y2
  float* bufB   = bufA + (size_t)64 * N;      // 64N : bias + x@Wr.T  (xr, then h1r)
  float* bufC   = bufB + (size_t)64 * N;      // 64N : agg1 -> h1 -> agg2 (in place)
  float* g      = bufC + (size_t)64 * N;      // 4096
  float* hbuf   = g + 4096;                   // 8192
  float* wt1l   = hbuf + 8192;                // 8192 floats (Wt4 for [64,128])
  float* wt1r   = wt1l + 8192;                // 8192
  float* wt2l   = wt1r + 8192;                // 4096 (Wt4 for [64,64])
  float* wt2r   = wt2l + 4096;                // 4096

  // zero deg; zero agg1 (bufC) and g (contiguous)
  hipMemsetAsync(deg, 0, (size_t)N * 4, stream);
  hipMemsetAsync(bufC, 0, ((size_t)64 * N + 4096) * 4, stream);

  wprep_k<<<8, 256, 0, stream>>>((const float4*)W1l, (float4*)wt1l, 32);
  wprep_k<<<8, 256, 0, stream>>>((const float4*)W1r, (float4*)wt1r, 32);
  wprep_k<<<4, 256, 0, stream>>>((const float4*)W2l, (float4*)wt2l, 16);
  wprep_k<<<4, 256, 0, stream>>>((const float4*)W2r, (float4*)wt2r, 16);

  degree_k<<<(E + 255) / 256, 256, 0, stream>>>(dst, deg, E);
  invdeg_k<<<(N + 255) / 256, 256, 0, stream>>>(deg, invdeg, N);

  // conv1: y1 = x@W1l.T -> bufA ; xr = b1l + x@W1r.T -> bufB
  gemm_dual_k<128><<<N / 32, 256, 0, stream>>>((const float4*)x, (const float4*)wt1l,
                                               (const float4*)wt1r, b1l, bufA, bufB);
  scatter_k<<<(E * 16) / 256, 256, 0, stream>>>((const float4*)bufA, src, dst, bufC, E);
  // h1 = agg1*invdeg + xr  (in place into bufC)
  h_fuse_k<<<(N * 16) / 256, 256, 0, stream>>>((float4*)bufC, (const float4*)bufB,
                                               invdeg, N * 16);

  // conv2: y2 = h1@W2l.T -> bufA ; h1r = b2l + h1@W2r.T -> bufB
  gemm_dual_k<64><<<N / 32, 256, 0, stream>>>((const float4*)bufC, (const float4*)wt2l,
                                              (const float4*)wt2r, b2l, bufA, bufB);
  hipMemsetAsync(bufC, 0, (size_t)64 * N * 4, stream);  // zero agg2
  scatter_k<<<(E * 16) / 256, 256, 0, stream>>>((const float4*)bufA, src, dst, bufC, E);

  // g[b] = mean over nodes of (agg2*invdeg + h1r)
  graph_mean_k<<<512, 256, 0, stream>>>(bufC, bufB, invdeg, g);
  mlp1_k<<<32, 256, 0, stream>>>(g, fc1_W, fc1_b, hbuf);
  mlp2_k<<<512, 256, 0, stream>>>(hbuf, fc2_W, fc2_b, out);
}

// Round 3
// 858.271 us; speedup vs baseline: 4.7564x; 4.7564x over previous
//
#include <hip/hip_runtime.h>
#include <hip/hip_bf16.h>

#define D_IN 128
#define D_EMB 64

// ---- weight prep: W[64][K] row-major -> Wt4[k4][j] = float4(W[j][4k4..4k4+3]) ----
__global__ __launch_bounds__(256) void wprep_k(const float4* __restrict__ W4,
                                               float4* __restrict__ out, int K4) {
  int idx = blockIdx.x * 256 + threadIdx.x;
  if (idx >= K4 * 64) return;
  int j = idx & 63, k4 = idx >> 6;
  out[idx] = W4[j * K4 + k4];
}

// ---- CSR build ----
__global__ __launch_bounds__(256) void degcnt_k(const int* __restrict__ dst,
                                                int* __restrict__ deg, int E) {
  int e = blockIdx.x * 256 + threadIdx.x;
  if (e < E) atomicAdd(deg + dst[e], 1);
}

__global__ __launch_bounds__(256) void invdeg_k(const int* __restrict__ deg,
                                                float* __restrict__ invdeg, int N) {
  int i = blockIdx.x * 256 + threadIdx.x;
  if (i < N) invdeg[i] = 1.0f / fmaxf((float)deg[i], 1.0f);
}

__global__ __launch_bounds__(256) void blocksum_k(const int* __restrict__ deg,
                                                  int* __restrict__ bsum) {
  __shared__ int sm[256];
  int t = threadIdx.x;
  sm[t] = deg[blockIdx.x * 256 + t];
  __syncthreads();
  for (int s = 128; s > 0; s >>= 1) {
    if (t < s) sm[t] += sm[t + s];
    __syncthreads();
  }
  if (t == 0) bsum[blockIdx.x] = sm[0];
}

// single block: exclusive scan of 512 block sums (in place)
__global__ __launch_bounds__(256) void scanbsum_k(int* __restrict__ bsum) {
  __shared__ int a[512], b[512];
  int t = threadIdx.x;
  a[t] = bsum[t];
  a[t + 256] = bsum[t + 256];
  __syncthreads();
  int* in = a;
  int* out = b;
  for (int st = 1; st < 512; st <<= 1) {
    for (int i = t; i < 512; i += 256) out[i] = in[i] + (i >= st ? in[i - st] : 0);
    __syncthreads();
    int* tmp = in; in = out; out = tmp;
  }
  for (int i = t; i < 512; i += 256) bsum[i] = (i == 0) ? 0 : in[i - 1];
}

// per-block inclusive scan of deg + block offset -> rowPtr (exclusive), cursor copy
__global__ __launch_bounds__(256) void rowptr_k(const int* __restrict__ deg,
                                                const int* __restrict__ bsumEx,
                                                int* __restrict__ rowPtr,
                                                int* __restrict__ cursor) {
  __shared__ int a[256], b[256];
  int t = threadIdx.x;
  int i = blockIdx.x * 256 + t;
  int d = deg[i];
  a[t] = d;
  __syncthreads();
  int* in = a;
  int* out = b;
  for (int st = 1; st < 256; st <<= 1) {
    out[t] = in[t] + (t >= st ? in[t - st] : 0);
    __syncthreads();
    int* tmp = in; in = out; out = tmp;
  }
  int incl = in[t] + bsumEx[blockIdx.x];
  rowPtr[i + 1] = incl;
  cursor[i] = incl - d;
  if (i == 0) rowPtr[0] = 0;
}

__global__ __launch_bounds__(256) void fill_k(const int* __restrict__ src,
                                              const int* __restrict__ dst,
                                              int* __restrict__ cursor,
                                              int* __restrict__ csr, int E) {
  int e = blockIdx.x * 256 + threadIdx.x;
  if (e < E) {
    int p = atomicAdd(cursor + dst[e], 1);
    csr[p] = src[e];
  }
}

// ---- dual GEMM: out1 = x @ W1.T ; out2 = bias2 + x @ W2.T  (x: [N,K], W*: [64,K]) ----
template <int K>
__global__ __launch_bounds__(256) void gemm_dual_k(const float4* __restrict__ x4,
                                                   const float4* __restrict__ wt1,
                                                   const float4* __restrict__ wt2,
                                                   const float* __restrict__ bias2,
                                                   float* __restrict__ out1,
                                                   float* __restrict__ out2) {
  constexpr int K4 = K / 4;
  const int t = threadIdx.x;
  const int j = t & 63;
  const int wv = t >> 6;
  const int nb = blockIdx.x * 32 + wv * 8;   // 32 nodes per block, 8 per wave
  float acc1[8], acc2[8];
  const float bj = bias2[j];
#pragma unroll
  for (int i = 0; i < 8; i++) { acc1[i] = 0.0f; acc2[i] = bj; }
  for (int k4 = 0; k4 < K4; k4++) {
    float4 w1 = wt1[k4 * 64 + j];
    float4 w2 = wt2[k4 * 64 + j];
#pragma unroll
    for (int i = 0; i < 8; i++) {
      float4 xv = x4[(size_t)(nb + i) * K4 + k4];
      acc1[i] += xv.x * w1.x + xv.y * w1.y + xv.z * w1.z + xv.w * w1.w;
      acc2[i] += xv.x * w2.x + xv.y * w2.y + xv.z * w2.z + xv.w * w2.w;
    }
  }
#pragma unroll
  for (int i = 0; i < 8; i++) {
    out1[(size_t)(nb + i) * 64 + j] = acc1[i];
    out2[(size_t)(nb + i) * 64 + j] = acc2[i];
  }
}

// ---- single GEMM: out1 = x @ W.T ----
template <int K>
__global__ __launch_bounds__(256) void gemm_single_k(const float4* __restrict__ x4,
                                                     const float4* __restrict__ wt1,
                                                     float* __restrict__ out1) {
  constexpr int K4 = K / 4;
  const int t = threadIdx.x;
  const int j = t & 63;
  const int wv = t >> 6;
  const int nb = blockIdx.x * 32 + wv * 8;
  float acc1[8];
#pragma unroll
  for (int i = 0; i < 8; i++) acc1[i] = 0.0f;
  for (int k4 = 0; k4 < K4; k4++) {
    float4 w1 = wt1[k4 * 64 + j];
#pragma unroll
    for (int i = 0; i < 8; i++) {
      float4 xv = x4[(size_t)(nb + i) * K4 + k4];
      acc1[i] += xv.x * w1.x + xv.y * w1.y + xv.z * w1.z + xv.w * w1.w;
    }
  }
#pragma unroll
  for (int i = 0; i < 8; i++) out1[(size_t)(nb + i) * 64 + j] = acc1[i];
}

// ---- gather aggregation, fused graph-mean accumulation ----
// wave per node (4 nodes/wave over i-loop), 16 lanes x float4 per edge row.
// WRITE_H=1: hio[n] = sum*invdeg + hio[n] (in-place), gmean += h/2048
// WRITE_H=0: gmean += (sum*invdeg)/2048  (h2 never materialized)
template <int WRITE_H>
__global__ __launch_bounds__(256) void gather_k(const float4* __restrict__ y4,
                                                const int* __restrict__ csr,
                                                const int* __restrict__ rowPtr,
                                                const float* __restrict__ invdeg,
                                                float4* __restrict__ hio,
                                                float* __restrict__ gmean) {
  __shared__ float4 sh4[4][16];
  const int t = threadIdx.x;
  const int lane = t & 63;
  const int wv = t >> 6;
  const int c = lane & 15;   // float4 chunk of the 64-float row
  const int eg = lane >> 4;  // edge group 0..3
  const int nb = blockIdx.x * 16;  // 16 consecutive nodes per block (same graph; 2048%16==0)
  float4 gacc = make_float4(0.f, 0.f, 0.f, 0.f);
  for (int i = 0; i < 4; i++) {
    int n = nb + wv * 4 + i;
    int base = rowPtr[n], end = rowPtr[n + 1];
    float4 acc = make_float4(0.f, 0.f, 0.f, 0.f);
    for (int e = base + eg; e < end; e += 4) {
      int s = csr[e];
      float4 v = y4[(size_t)s * 16 + c];
      acc.x += v.x; acc.y += v.y; acc.z += v.z; acc.w += v.w;
    }
#pragma unroll
    for (int m = 16; m <= 32; m <<= 1) {
      acc.x += __shfl_xor(acc.x, m, 64);
      acc.y += __shfl_xor(acc.y, m, 64);
      acc.z += __shfl_xor(acc.z, m, 64);
      acc.w += __shfl_xor(acc.w, m, 64);
    }
    if (eg == 0) {
      float sc = invdeg[n];
      float4 h;
      if (WRITE_H) {
        float4 o = hio[(size_t)n * 16 + c];
        h = make_float4(acc.x * sc + o.x, acc.y * sc + o.y,
                        acc.z * sc + o.z, acc.w * sc + o.w);
        hio[(size_t)n * 16 + c] = h;
      } else {
        h = make_float4(acc.x * sc, acc.y * sc, acc.z * sc, acc.w * sc);
      }
      gacc.x += h.x; gacc.y += h.y; gacc.z += h.z; gacc.w += h.w;
    }
  }
  if (eg == 0) sh4[wv][c] = gacc;
  __syncthreads();
  if (wv == 0 && eg == 0) {
    float4 t0 = sh4[0][c], t1 = sh4[1][c], t2 = sh4[2][c], t3 = sh4[3][c];
    float4 tot = make_float4(t0.x + t1.x + t2.x + t3.x, t0.y + t1.y + t2.y + t3.y,
                             t0.z + t1.z + t2.z + t3.z, t0.w + t1.w + t2.w + t3.w);
    const float s = 1.0f / 2048.0f;
    int graph = nb >> 11;
    float* gp = gmean + graph * 64 + c * 4;
    atomicAdd(gp + 0, tot.x * s);
    atomicAdd(gp + 1, tot.y * s);
    atomicAdd(gp + 2, tot.z * s);
    atomicAdd(gp + 3, tot.w * s);
  }
}

// ---- g[b][j] = gmean2[b][j] + b2l[j] + sum_k gmean1[b][k] * W2r[j][k] ----
__global__ __launch_bounds__(256) void combine_k(const float* __restrict__ gmean2,
                                                 const float* __restrict__ gmean1,
                                                 const float* __restrict__ b2l,
                                                 const float* __restrict__ W2r,
                                                 float* __restrict__ g) {
  int idx = blockIdx.x * 256 + threadIdx.x;   // 4096
  int b = idx >> 6, j = idx & 63;
  const float4* m4 = (const float4*)(gmean1 + b * 64);
  const float4* w4 = (const float4*)(W2r + j * 64);
  float acc = gmean2[idx] + b2l[j];
#pragma unroll
  for (int k4 = 0; k4 < 16; k4++) {
    float4 mv = m4[k4], wv = w4[k4];
    acc += mv.x * wv.x + mv.y * wv.y + mv.z * wv.z + mv.w * wv.w;
  }
  g[idx] = acc;
}

// ---- h = relu(g @ fc1_W.T + fc1_b)   g:[64,64] fc1_W:[128,64] -> h:[64,128] ----
__global__ __launch_bounds__(256) void mlp1_k(const float* __restrict__ g,
                                              const float* __restrict__ fc1_W,
                                              const float* __restrict__ fc1_b,
                                              float* __restrict__ h) {
  int idx = blockIdx.x * 256 + threadIdx.x;
  int b = idx >> 7, k = idx & 127;
  const float4* g4 = (const float4*)(g + b * 64);
  const float4* w4 = (const float4*)(fc1_W + k * 64);
  float acc = fc1_b[k];
#pragma unroll
  for (int j4 = 0; j4 < 16; j4++) {
    float4 gv = g4[j4], wv = w4[j4];
    acc += gv.x * wv.x + gv.y * wv.y + gv.z * wv.z + gv.w * wv.w;
  }
  h[idx] = fmaxf(acc, 0.0f);
}

// ---- q = h @ fc2_W.T + fc2_b   h:[64,128] fc2_W:[2048,128] -> q:[64,2048] ----
__global__ __launch_bounds__(256) void mlp2_k(const float* __restrict__ h,
                                              const float* __restrict__ fc2_W,
                                              const float* __restrict__ fc2_b,
                                              float* __restrict__ out) {
  __shared__ float4 sh[32];
  int b = blockIdx.x >> 3;
  int a = (blockIdx.x & 7) * 256 + threadIdx.x;
  if (threadIdx.x < 32) sh[threadIdx.x] = ((const float4*)(h + b * 128))[threadIdx.x];
  __syncthreads();
  const float4* w4 = (const float4*)(fc2_W + (size_t)a * 128);
  float acc = fc2_b[a];
#pragma unroll
  for (int k4 = 0; k4 < 32; k4++) {
    float4 hv = sh[k4], wv = w4[k4];
    acc += hv.x * wv.x + hv.y * wv.y + hv.z * wv.z + hv.w * wv.w;
  }
  out[b * 2048 + a] = acc;
}

extern "C" void kernel_launch(void* const* d_in, const int* in_sizes, int n_in,
                              void* d_out, int out_size, void* d_ws, size_t ws_size,
                              hipStream_t stream) {
  const float* x     = (const float*)d_in[0];
  const int*   ei    = (const int*)d_in[1];
  const float* W1l   = (const float*)d_in[2];
  const float* b1l   = (const float*)d_in[3];
  const float* W1r   = (const float*)d_in[4];
  const float* W2l   = (const float*)d_in[5];
  const float* b2l   = (const float*)d_in[6];
  const float* W2r   = (const float*)d_in[7];
  const float* fc1_W = (const float*)d_in[8];
  const float* fc1_b = (const float*)d_in[9];
  const float* fc2_W = (const float*)d_in[10];
  const float* fc2_b = (const float*)d_in[11];
  float* out = (float*)d_out;

  const int N = in_sizes[0] / D_IN;   // 131072
  const int E = in_sizes[1] / 2;      // 2097152
  const int* src = ei;
  const int* dst = ei + E;

  // workspace layout (~78 MiB total; round-1 proved >= 97 MiB is available)
  char* ws = (char*)d_ws;
  int*   deg    = (int*)ws;     ws += (size_t)N * 4;
  int*   cursor = (int*)ws;     ws += (size_t)N * 4;
  int*   rowPtr = (int*)ws;     ws += (size_t)(N + 256) * 4;
  int*   bsum   = (int*)ws;     ws += 512 * 4;
  float* invdeg = (float*)ws;   ws += (size_t)N * 4;
  float* gmean1 = (float*)ws;   ws += 4096 * 4;
  float* gmean2 = (float*)ws;   ws += 4096 * 4;
  float* g      = (float*)ws;   ws += 4096 * 4;
  float* hbuf   = (float*)ws;   ws += 8192 * 4;
  float* wt1l   = (float*)ws;   ws += 8192 * 4;
  float* wt1r   = (float*)ws;   ws += 8192 * 4;
  float* wt2l   = (float*)ws;   ws += 4096 * 4;
  int*   csr    = (int*)ws;     ws += (size_t)E * 4;
  float* bufA   = (float*)ws;   ws += (size_t)64 * N * 4;  // y1, then y2
  float* bufB   = (float*)ws;   ws += (size_t)64 * N * 4;  // xr -> h1 (in place)

  hipMemsetAsync(deg, 0, (size_t)N * 4, stream);
  hipMemsetAsync(gmean1, 0, 2 * 4096 * 4, stream);   // gmean1 + gmean2 contiguous

  wprep_k<<<8, 256, 0, stream>>>((const float4*)W1l, (float4*)wt1l, 32);
  wprep_k<<<8, 256, 0, stream>>>((const float4*)W1r, (float4*)wt1r, 32);
  wprep_k<<<4, 256, 0, stream>>>((const float4*)W2l, (float4*)wt2l, 16);

  // CSR build (reused by both convs)
  degcnt_k<<<(E + 255) / 256, 256, 0, stream>>>(dst, deg, E);
  invdeg_k<<<(N + 255) / 256, 256, 0, stream>>>(deg, invdeg, N);
  blocksum_k<<<N / 256, 256, 0, stream>>>(deg, bsum);
  scanbsum_k<<<1, 256, 0, stream>>>(bsum);
  rowptr_k<<<N / 256, 256, 0, stream>>>(deg, bsum, rowPtr, cursor);
  fill_k<<<(E + 255) / 256, 256, 0, stream>>>(src, dst, cursor, csr, E);

  // conv1: y1 = x@W1l.T -> bufA ; xr = b1l + x@W1r.T -> bufB
  gemm_dual_k<128><<<N / 32, 256, 0, stream>>>((const float4*)x, (const float4*)wt1l,
                                               (const float4*)wt1r, b1l, bufA, bufB);
  // h1 = gather(y1)*invdeg + xr -> bufB in place; gmean1 += h1/2048
  gather_k<1><<<N / 16, 256, 0, stream>>>((const float4*)bufA, csr, rowPtr, invdeg,
                                          (float4*)bufB, gmean1);

  // conv2: y2 = h1@W2l.T -> bufA
  gemm_single_k<64><<<N / 32, 256, 0, stream>>>((const float4*)bufB, (const float4*)wt2l,
                                                bufA);
  // gmean2 += gather(y2)*invdeg / 2048  (h2 never materialized)
  gather_k<0><<<N / 16, 256, 0, stream>>>((const float4*)bufA, csr, rowPtr, invdeg,
                                          nullptr, gmean2);

  // g = gmean2 + b2l + gmean1 @ W2r.T
  combine_k<<<16, 256, 0, stream>>>(gmean2, gmean1, b2l, W2r, g);
  mlp1_k<<<32, 256, 0, stream>>>(g, fc1_W, fc1_b, hbuf);
  mlp2_k<<<512, 256, 0, stream>>>(hbuf, fc2_W, fc2_b, out);
}

// Round 5
// 713.495 us; speedup vs baseline: 5.7215x; 1.2029x over previous
//
#include <hip/hip_runtime.h>
#include <hip/hip_bf16.h>

#define D_IN 128
#define D_EMB 64

// ---- weight prep: W[64][K] row-major -> Wt4[k4][j] = float4(W[j][4k4..4k4+3]) ----
__global__ __launch_bounds__(256) void wprep_k(const float4* __restrict__ W4,
                                               float4* __restrict__ out, int K4) {
  int idx = blockIdx.x * 256 + threadIdx.x;
  if (idx >= K4 * 64) return;
  int j = idx & 63, k4 = idx >> 6;
  out[idx] = W4[j * K4 + k4];
}

// ---- CSR build ----
__global__ __launch_bounds__(256) void degcnt_k(const int* __restrict__ dst,
                                                int* __restrict__ deg, int E) {
  int e = blockIdx.x * 256 + threadIdx.x;
  if (e < E) atomicAdd(deg + dst[e], 1);
}

__global__ __launch_bounds__(256) void invdeg_k(const int* __restrict__ deg,
                                                float* __restrict__ invdeg, int N) {
  int i = blockIdx.x * 256 + threadIdx.x;
  if (i < N) invdeg[i] = 1.0f / fmaxf((float)deg[i], 1.0f);
}

__global__ __launch_bounds__(256) void blocksum_k(const int* __restrict__ deg,
                                                  int* __restrict__ bsum) {
  __shared__ int sm[256];
  int t = threadIdx.x;
  sm[t] = deg[blockIdx.x * 256 + t];
  __syncthreads();
  for (int s = 128; s > 0; s >>= 1) {
    if (t < s) sm[t] += sm[t + s];
    __syncthreads();
  }
  if (t == 0) bsum[blockIdx.x] = sm[0];
}

// single block: exclusive scan of 512 block sums (in place)
__global__ __launch_bounds__(256) void scanbsum_k(int* __restrict__ bsum) {
  __shared__ int a[512], b[512];
  int t = threadIdx.x;
  a[t] = bsum[t];
  a[t + 256] = bsum[t + 256];
  __syncthreads();
  int* in = a;
  int* out = b;
  for (int st = 1; st < 512; st <<= 1) {
    for (int i = t; i < 512; i += 256) out[i] = in[i] + (i >= st ? in[i - st] : 0);
    __syncthreads();
    int* tmp = in; in = out; out = tmp;
  }
  for (int i = t; i < 512; i += 256) bsum[i] = (i == 0) ? 0 : in[i - 1];
}

// per-block inclusive scan of deg + block offset -> rowPtr (exclusive), cursor copy
__global__ __launch_bounds__(256) void rowptr_k(const int* __restrict__ deg,
                                                const int* __restrict__ bsumEx,
                                                int* __restrict__ rowPtr,
                                                int* __restrict__ cursor) {
  __shared__ int a[256], b[256];
  int t = threadIdx.x;
  int i = blockIdx.x * 256 + t;
  int d = deg[i];
  a[t] = d;
  __syncthreads();
  int* in = a;
  int* out = b;
  for (int st = 1; st < 256; st <<= 1) {
    out[t] = in[t] + (t >= st ? in[t - st] : 0);
    __syncthreads();
    int* tmp = in; in = out; out = tmp;
  }
  int incl = in[t] + bsumEx[blockIdx.x];
  rowPtr[i + 1] = incl;
  cursor[i] = incl - d;
  if (i == 0) rowPtr[0] = 0;
}

__global__ __launch_bounds__(256) void fill_k(const int* __restrict__ src,
                                              const int* __restrict__ dst,
                                              int* __restrict__ cursor,
                                              int* __restrict__ csr, int E) {
  int e = blockIdx.x * 256 + threadIdx.x;
  if (e < E) {
    int p = atomicAdd(cursor + dst[e], 1);
    csr[p] = src[e];
  }
}

// ---- GEMM with LDS-staged x tile. 32 nodes/block, 4 waves x 8 nodes.
// out1 = bf16(x @ W1.T) ; DUAL: out2 = fp32(bias2 + x @ W2.T)
template <int K, int DUAL>
__global__ __launch_bounds__(256) void gemm_k(const float4* __restrict__ x4,
                                              const float4* __restrict__ wt1,
                                              const float4* __restrict__ wt2,
                                              const float* __restrict__ bias2,
                                              __hip_bfloat16* __restrict__ out1,
                                              float* __restrict__ out2) {
  constexpr int K4 = K / 4;
  __shared__ float4 sx[32 * K4];
  const int t = threadIdx.x;
  const int nb = blockIdx.x * 32;
  // coalesced staging: x rows are contiguous, so this is one linear range
#pragma unroll
  for (int idx = t; idx < 32 * K4; idx += 256) sx[idx] = x4[(size_t)nb * K4 + idx];
  __syncthreads();
  const int j = t & 63;
  const int wv = t >> 6;
  const int r0 = wv * 8;
  float acc1[8], acc2[8];
  const float bj = DUAL ? bias2[j] : 0.0f;
#pragma unroll
  for (int i = 0; i < 8; i++) { acc1[i] = 0.0f; acc2[i] = bj; }
  for (int k4 = 0; k4 < K4; k4++) {
    float4 w1 = wt1[k4 * 64 + j];
    float4 w2;
    if (DUAL) w2 = wt2[k4 * 64 + j];
#pragma unroll
    for (int i = 0; i < 8; i++) {
      float4 xv = sx[(r0 + i) * K4 + k4];   // broadcast ds_read_b128
      acc1[i] += xv.x * w1.x + xv.y * w1.y + xv.z * w1.z + xv.w * w1.w;
      if (DUAL)
        acc2[i] += xv.x * w2.x + xv.y * w2.y + xv.z * w2.z + xv.w * w2.w;
    }
  }
#pragma unroll
  for (int i = 0; i < 8; i++) {
    out1[(size_t)(nb + r0 + i) * 64 + j] = __float2bfloat16(acc1[i]);
    if (DUAL) out2[(size_t)(nb + r0 + i) * 64 + j] = acc2[i];
  }
}

// ---- gather aggregation over bf16 messages, fused graph-mean accumulation ----
// wave per node (4 nodes/wave), 16 lanes x 4 bf16 (ushort4, 8B) per edge row (128 B).
// Edge index read: all 16 lanes of a group load csr[e] directly (HW broadcast) —
// NO cross-lane shfl of edge ids (shfl from a lane that exited the divergent loop
// is undefined on CDNA and caused the round-2/round-4 5.39e-2 failures).
// WRITE_H=1: hio[n] = sum*invdeg + hio[n] (in-place fp32), gmean += h/2048
// WRITE_H=0: gmean += (sum*invdeg)/2048  (h2 never materialized)
template <int WRITE_H>
__global__ __launch_bounds__(256) void gather_k(const ushort4* __restrict__ yb,
                                                const int* __restrict__ csr,
                                                const int* __restrict__ rowPtr,
                                                const float* __restrict__ invdeg,
                                                float4* __restrict__ hio,
                                                float* __restrict__ gmean) {
  __shared__ float4 sh4[4][16];
  const int t = threadIdx.x;
  const int lane = t & 63;
  const int wv = t >> 6;
  const int c = lane & 15;   // which ushort4 (4 bf16) of the 64-elem row
  const int eg = lane >> 4;  // edge group 0..3
  const int nb = blockIdx.x * 16;  // 16 consecutive nodes per block (2048%16==0 -> same graph)
  float4 gacc = make_float4(0.f, 0.f, 0.f, 0.f);
  for (int i = 0; i < 4; i++) {
    int n = nb + wv * 4 + i;
    int base = rowPtr[n], end = rowPtr[n + 1];
    float4 acc = make_float4(0.f, 0.f, 0.f, 0.f);
    for (int e = base + eg; e < end; e += 4) {
      int s = csr[e];
      ushort4 v = yb[(size_t)s * 16 + c];
      acc.x += __uint_as_float((unsigned)v.x << 16);
      acc.y += __uint_as_float((unsigned)v.y << 16);
      acc.z += __uint_as_float((unsigned)v.z << 16);
      acc.w += __uint_as_float((unsigned)v.w << 16);
    }
#pragma unroll
    for (int m = 16; m <= 32; m <<= 1) {
      acc.x += __shfl_xor(acc.x, m, 64);
      acc.y += __shfl_xor(acc.y, m, 64);
      acc.z += __shfl_xor(acc.z, m, 64);
      acc.w += __shfl_xor(acc.w, m, 64);
    }
    if (eg == 0) {
      float sc = invdeg[n];
      float4 h;
      if (WRITE_H) {
        float4 o = hio[(size_t)n * 16 + c];
        h = make_float4(acc.x * sc + o.x, acc.y * sc + o.y,
                        acc.z * sc + o.z, acc.w * sc + o.w);
        hio[(size_t)n * 16 + c] = h;
      } else {
        h = make_float4(acc.x * sc, acc.y * sc, acc.z * sc, acc.w * sc);
      }
      gacc.x += h.x; gacc.y += h.y; gacc.z += h.z; gacc.w += h.w;
    }
  }
  if (eg == 0) sh4[wv][c] = gacc;
  __syncthreads();
  if (wv == 0 && eg == 0) {
    float4 t0 = sh4[0][c], t1 = sh4[1][c], t2 = sh4[2][c], t3 = sh4[3][c];
    float4 tot = make_float4(t0.x + t1.x + t2.x + t3.x, t0.y + t1.y + t2.y + t3.y,
                             t0.z + t1.z + t2.z + t3.z, t0.w + t1.w + t2.w + t3.w);
    const float s = 1.0f / 2048.0f;
    int graph = nb >> 11;
    float* gp = gmean + graph * 64 + c * 4;
    atomicAdd(gp + 0, tot.x * s);
    atomicAdd(gp + 1, tot.y * s);
    atomicAdd(gp + 2, tot.z * s);
    atomicAdd(gp + 3, tot.w * s);
  }
}

// ---- g[b][j] = gmean2[b][j] + b2l[j] + sum_k gmean1[b][k] * W2r[j][k] ----
__global__ __launch_bounds__(256) void combine_k(const float* __restrict__ gmean2,
                                                 const float* __restrict__ gmean1,
                                                 const float* __restrict__ b2l,
                                                 const float* __restrict__ W2r,
                                                 float* __restrict__ g) {
  int idx = blockIdx.x * 256 + threadIdx.x;   // 4096
  int b = idx >> 6, j = idx & 63;
  const float4* m4 = (const float4*)(gmean1 + b * 64);
  const float4* w4 = (const float4*)(W2r + j * 64);
  float acc = gmean2[idx] + b2l[j];
#pragma unroll
  for (int k4 = 0; k4 < 16; k4++) {
    float4 mv = m4[k4], wv = w4[k4];
    acc += mv.x * wv.x + mv.y * wv.y + mv.z * wv.z + mv.w * wv.w;
  }
  g[idx] = acc;
}

// ---- h = relu(g @ fc1_W.T + fc1_b)   g:[64,64] fc1_W:[128,64] -> h:[64,128] ----
__global__ __launch_bounds__(256) void mlp1_k(const float* __restrict__ g,
                                              const float* __restrict__ fc1_W,
                                              const float* __restrict__ fc1_b,
                                              float* __restrict__ h) {
  int idx = blockIdx.x * 256 + threadIdx.x;
  int b = idx >> 7, k = idx & 127;
  const float4* g4 = (const float4*)(g + b * 64);
  const float4* w4 = (const float4*)(fc1_W + k * 64);
  float acc = fc1_b[k];
#pragma unroll
  for (int j4 = 0; j4 < 16; j4++) {
    float4 gv = g4[j4], wv = w4[j4];
    acc += gv.x * wv.x + gv.y * wv.y + gv.z * wv.z + gv.w * wv.w;
  }
  h[idx] = fmaxf(acc, 0.0f);
}

// ---- q = h @ fc2_W.T + fc2_b   h:[64,128] fc2_W:[2048,128] -> q:[64,2048] ----
__global__ __launch_bounds__(256) void mlp2_k(const float* __restrict__ h,
                                              const float* __restrict__ fc2_W,
                                              const float* __restrict__ fc2_b,
                                              float* __restrict__ out) {
  __shared__ float4 sh[32];
  int b = blockIdx.x >> 3;
  int a = (blockIdx.x & 7) * 256 + threadIdx.x;
  if (threadIdx.x < 32) sh[threadIdx.x] = ((const float4*)(h + b * 128))[threadIdx.x];
  __syncthreads();
  const float4* w4 = (const float4*)(fc2_W + (size_t)a * 128);
  float acc = fc2_b[a];
#pragma unroll
  for (int k4 = 0; k4 < 32; k4++) {
    float4 hv = sh[k4], wv = w4[k4];
    acc += hv.x * wv.x + hv.y * wv.y + hv.z * wv.z + hv.w * wv.w;
  }
  out[b * 2048 + a] = acc;
}

extern "C" void kernel_launch(void* const* d_in, const int* in_sizes, int n_in,
                              void* d_out, int out_size, void* d_ws, size_t ws_size,
                              hipStream_t stream) {
  const float* x     = (const float*)d_in[0];
  const int*   ei    = (const int*)d_in[1];
  const float* W1l   = (const float*)d_in[2];
  const float* b1l   = (const float*)d_in[3];
  const float* W1r   = (const float*)d_in[4];
  const float* W2l   = (const float*)d_in[5];
  const float* b2l   = (const float*)d_in[6];
  const float* W2r   = (const float*)d_in[7];
  const float* fc1_W = (const float*)d_in[8];
  const float* fc1_b = (const float*)d_in[9];
  const float* fc2_W = (const float*)d_in[10];
  const float* fc2_b = (const float*)d_in[11];
  float* out = (float*)d_out;

  const int N = in_sizes[0] / D_IN;   // 131072
  const int E = in_sizes[1] / 2;      // 2097152
  const int* src = ei;
  const int* dst = ei + E;

  // workspace layout (~59 MiB total; 78 MiB proven available in round 3)
  char* ws = (char*)d_ws;
  int*   deg    = (int*)ws;     ws += (size_t)N * 4;
  int*   cursor = (int*)ws;     ws += (size_t)N * 4;
  int*   rowPtr = (int*)ws;     ws += (size_t)(N + 256) * 4;
  int*   bsum   = (int*)ws;     ws += 512 * 4;
  float* invdeg = (float*)ws;   ws += (size_t)N * 4;
  float* gmean1 = (float*)ws;   ws += 4096 * 4;
  float* gmean2 = (float*)ws;   ws += 4096 * 4;
  float* g      = (float*)ws;   ws += 4096 * 4;
  float* hbuf   = (float*)ws;   ws += 8192 * 4;
  float* wt1l   = (float*)ws;   ws += 8192 * 4;
  float* wt1r   = (float*)ws;   ws += 8192 * 4;
  float* wt2l   = (float*)ws;   ws += 4096 * 4;
  int*   csr    = (int*)ws;     ws += (size_t)E * 4;
  __hip_bfloat16* bufA = (__hip_bfloat16*)ws;  ws += (size_t)64 * N * 2;  // y1/y2 bf16
  float* bufB   = (float*)ws;   ws += (size_t)64 * N * 4;  // xr -> h1 (in place, fp32)

  hipMemsetAsync(deg, 0, (size_t)N * 4, stream);
  hipMemsetAsync(gmean1, 0, 2 * 4096 * 4, stream);   // gmean1 + gmean2 contiguous

  wprep_k<<<8, 256, 0, stream>>>((const float4*)W1l, (float4*)wt1l, 32);
  wprep_k<<<8, 256, 0, stream>>>((const float4*)W1r, (float4*)wt1r, 32);
  wprep_k<<<4, 256, 0, stream>>>((const float4*)W2l, (float4*)wt2l, 16);

  // CSR build (reused by both convs)
  degcnt_k<<<(E + 255) / 256, 256, 0, stream>>>(dst, deg, E);
  invdeg_k<<<(N + 255) / 256, 256, 0, stream>>>(deg, invdeg, N);
  blocksum_k<<<N / 256, 256, 0, stream>>>(deg, bsum);
  scanbsum_k<<<1, 256, 0, stream>>>(bsum);
  rowptr_k<<<N / 256, 256, 0, stream>>>(deg, bsum, rowPtr, cursor);
  fill_k<<<(E + 255) / 256, 256, 0, stream>>>(src, dst, cursor, csr, E);

  // conv1: y1 = bf16(x@W1l.T) -> bufA ; xr = b1l + x@W1r.T -> bufB (fp32)
  gemm_k<128, 1><<<N / 32, 256, 0, stream>>>((const float4*)x, (const float4*)wt1l,
                                             (const float4*)wt1r, b1l, bufA, bufB);
  // h1 = gather(y1)*invdeg + xr -> bufB in place; gmean1 += h1/2048
  gather_k<1><<<N / 16, 256, 0, stream>>>((const ushort4*)bufA, csr, rowPtr, invdeg,
                                          (float4*)bufB, gmean1);

  // conv2: y2 = bf16(h1@W2l.T) -> bufA
  gemm_k<64, 0><<<N / 32, 256, 0, stream>>>((const float4*)bufB, (const float4*)wt2l,
                                            nullptr, nullptr, bufA, nullptr);
  // gmean2 += gather(y2)*invdeg / 2048  (h2 never materialized)
  gather_k<0><<<N / 16, 256, 0, stream>>>((const ushort4*)bufA, csr, rowPtr, invdeg,
                                          nullptr, gmean2);

  // g = gmean2 + b2l + gmean1 @ W2r.T
  combine_k<<<16, 256, 0, stream>>>(gmean2, gmean1, b2l, W2r, g);
  mlp1_k<<<32, 256, 0, stream>>>(g, fc1_W, fc1_b, hbuf);
  mlp2_k<<<512, 256, 0, stream>>>(hbuf, fc2_W, fc2_b, out);
}